// Round 9
// baseline (354.264 us; speedup 1.0000x reference)
//
#include <hip/hip_runtime.h>
#include <hip/hip_bf16.h>

// GroupNLMSMemory: B=512, D=256, M=100000
// out = [retrieved 512x256 | attn 512x100000] (f32)
// r9: fuse sum-pass into K-preprocess. Path A:
//   k0(xb) -> kA(Knorm+KB+QK+exp+chunk sums -> PSTAT in attn tail)
//   -> k0b(VT) -> k2A(1/l) -> k3a(r8-exact) -> k4
// Path B fallback unchanged (k0c<false>, k3b, k2<112>, k5, k4<false>).

#define MCOLS 100000
#define MP    100032
#define DDIM  256
#define CHUNK 1792                 // k3: 28 tiles of 64
#define NTFULL 28
#define NCHUNK 56
#define NSLOT 56
#define NCHA  1563                 // kA chunks of 64 m
#define PSTAT_OFF 50530816         // floats: 131072+51200000-1563*512
#define ATTN_OFF 131072
#define WS_RXN  0
#define WS_RKN  512
#define WS_RCPL 100512
#define WS_XB_BYTE   409600ull
#define WS_VT_BYTE   1048576ull
#define WS_PART_BYTE 52264960ull
#define WS_KB_BYTE   84246528ull
#define WS_KB_END    (WS_KB_BYTE + 2ull*(size_t)MCOLS*DDIM) // 135,446,528

#define GLL(g, l) __builtin_amdgcn_global_load_lds( \
    (const __attribute__((address_space(1))) void*)(g), \
    (__attribute__((address_space(3))) void*)(l), 16, 0, 0)

typedef short short8 __attribute__((ext_vector_type(8)));
typedef float f32x4  __attribute__((ext_vector_type(4)));

static __device__ __forceinline__ unsigned short f2bfu(float f) {
  union { __hip_bfloat16 h; unsigned short u; } cv;
  cv.h = __float2bfloat16(f);
  return cv.u;
}
static __device__ __forceinline__ unsigned int pk2(float a, float b) {
  return (unsigned int)f2bfu(a) | ((unsigned int)f2bfu(b) << 16);
}
static __device__ __forceinline__ short8 pack8(float4 a, float4 b) {
  short8 r;
  r[0] = (short)f2bfu(a.x); r[1] = (short)f2bfu(a.y);
  r[2] = (short)f2bfu(a.z); r[3] = (short)f2bfu(a.w);
  r[4] = (short)f2bfu(b.x); r[5] = (short)f2bfu(b.y);
  r[6] = (short)f2bfu(b.z); r[7] = (short)f2bfu(b.w);
  return r;
}

// ---------------- k0: x norms -> rxn + xb = bf16(10*x/|x|) ----------------
__global__ void k0_xn(const float* __restrict__ x, float* __restrict__ ws) {
  const int b = blockIdx.x, t = threadIdx.x;
  const float v = x[b*DDIM + t];
  float s = v*v;
  #pragma unroll
  for (int mk = 1; mk <= 32; mk <<= 1) s += __shfl_xor(s, mk);
  __shared__ float ps[4];
  if ((t & 63) == 0) ps[t >> 6] = s;
  __syncthreads();
  const float tot = ps[0] + ps[1] + ps[2] + ps[3];
  const float r10 = 10.0f / fmaxf(sqrtf(tot), 1e-12f);
  if (t == 0) ws[WS_RXN + b] = r10;
  unsigned short* xbp = (unsigned short*)((char*)ws + WS_XB_BYTE);
  xbp[b*DDIM + t] = f2bfu(v * r10);
}

// ---------------- kA: fused K-norm + KB write + QK + exp + chunk sums ----------------
__global__ __launch_bounds__(512, 4) void kA_fused(const float* __restrict__ K,
                                                   float* __restrict__ ws,
                                                   float* __restrict__ out) {
  const int c = blockIdx.x;                    // 64-m chunk
  const int m0 = c*64;
  const int t = threadIdx.x;
  __shared__ __align__(16) unsigned short klds[64][264];  // +8 short pad (33.8KB)
  // ---- phase 1: load K rows (coalesced), norm, write KB, stage LDS ----
  {
    const int ml = t >> 3, tc = t & 7;         // row ml, 32-col group tc
    const int mg = m0 + ml;
    const bool mok = mg < MCOLS;
    const float* kp = K + (size_t)(mok ? mg : MCOLS-1)*DDIM + 32*tc;
    float4 buf[8];
    float ss = 0.f;
    #pragma unroll
    for (int j = 0; j < 8; ++j) {
      buf[j] = *(const float4*)(kp + 4*j);
      ss += buf[j].x*buf[j].x + buf[j].y*buf[j].y + buf[j].z*buf[j].z + buf[j].w*buf[j].w;
    }
    ss += __shfl_xor(ss, 1); ss += __shfl_xor(ss, 2); ss += __shfl_xor(ss, 4);
    const float rk = mok ? (1.0f / fmaxf(sqrtf(ss), 1e-12f)) : 0.f;  // 0 -> zero rows
    unsigned int* kb = (unsigned int*)((char*)ws + WS_KB_BYTE);
    #pragma unroll
    for (int j = 0; j < 4; ++j) {
      const float4 a = buf[2*j], b2 = buf[2*j+1];
      uint4 u;
      u.x = pk2(a.x*rk, a.y*rk);   u.y = pk2(a.z*rk, a.w*rk);
      u.z = pk2(b2.x*rk, b2.y*rk); u.w = pk2(b2.z*rk, b2.w*rk);
      const int slot = 4*tc + j;
      if (mok) *(uint4*)(kb + (size_t)mg*128 + (slot ^ (ml & 7))*4) = u;  // KB layout (k3a)
      *(uint4*)&klds[ml][slot*8] = u;          // local: linear slots, pad banks
    }
  }
  __syncthreads();
  // ---- phase 2: QK for all 512 x-rows vs this 64-m tile ----
  const int w = t >> 6, l = t & 63, q = l >> 4, ln = l & 15;
  const unsigned short* xb = (const unsigned short*)((const char*)ws + WS_XB_BYTE);
  float* pst = out + PSTAT_OFF + (size_t)c*512;
  #pragma unroll 1
  for (int as = 0; as < 4; ++as) {
    const int xrow = 64*w + 16*as + ln;
    short8 xf[8];
    #pragma unroll
    for (int kk = 0; kk < 8; ++kk)
      xf[kk] = *(const short8*)(xb + xrow*DDIM + 32*kk + 8*q);
    f32x4 acc[4];
    #pragma unroll
    for (int mm = 0; mm < 4; ++mm) { f32x4 z = {0.f,0.f,0.f,0.f}; acc[mm] = z; }
    #pragma unroll
    for (int kk = 0; kk < 8; ++kk) {
      #pragma unroll
      for (int mm = 0; mm < 4; ++mm) {
        const short8 b = *(const short8*)((const char*)&klds[0][0]
                                          + (16*mm + ln)*528 + (4*kk + q)*16);
        acc[mm] = __builtin_amdgcn_mfma_f32_16x16x32_bf16(xf[kk], b, acc[mm], 0,0,0);
      }
    }
    float srow[4] = {0.f, 0.f, 0.f, 0.f};
    #pragma unroll
    for (int mm = 0; mm < 4; ++mm) {
      const bool ok = (m0 + 16*mm + ln) < MCOLS;
      #pragma unroll
      for (int r = 0; r < 4; ++r)
        srow[r] += ok ? __expf(acc[mm][r]) : 0.f;
    }
    #pragma unroll
    for (int r = 0; r < 4; ++r) {
      float s = srow[r];
      s += __shfl_xor(s, 1); s += __shfl_xor(s, 2);
      s += __shfl_xor(s, 4); s += __shfl_xor(s, 8);
      if (ln == 0) pst[64*w + 16*as + 4*q + r] = s;
    }
  }
}

// ---------------- k2A: reduce 1563 chunk sums -> 1/l ----------------
__global__ void k2A_final(const float* __restrict__ out, float* __restrict__ ws) {
  const int b = blockIdx.x, t = threadIdx.x;   // 512 x 256
  const float* pst = out + PSTAT_OFF;
  float v = 0.f;
  for (int ch = t; ch < NCHA; ch += 256)
    v += pst[(size_t)ch*512 + b];
  #pragma unroll
  for (int mk = 1; mk <= 32; mk <<= 1) v += __shfl_xor(v, mk);
  __shared__ float s2[4];
  if ((t & 63) == 0) s2[t >> 6] = v;
  __syncthreads();
  if (t == 0) ws[WS_RCPL + b] = 1.0f / (s2[0] + s2[1] + s2[2] + s2[3]);
}

// ---------------- k0c (path B only): K norms ----------------
__global__ __launch_bounds__(256) void k0c_kn(const float* __restrict__ K,
                                              float* __restrict__ ws) {
  const int t = threadIdx.x;
  const int mg = blockIdx.x*64 + (t >> 2);
  const int qq = t & 3;
  if (mg >= MCOLS) return;
  const float* kp = K + (size_t)mg*DDIM + 64*qq;
  float ss = 0.f;
  #pragma unroll
  for (int j = 0; j < 16; ++j) {
    const float4 a = *(const float4*)(kp + 4*j);
    ss += a.x*a.x + a.y*a.y + a.z*a.z + a.w*a.w;
  }
  ss += __shfl_xor(ss, 1); ss += __shfl_xor(ss, 2);
  if (qq == 0) ws[WS_RKN + mg] = 1.0f / fmaxf(sqrtf(ss), 1e-12f);
}

// ---------------- k0b: V -> VT bf16 [256][MP], slot^(d&7) swizzled ----------------
__global__ __launch_bounds__(256) void k0b_tr(const float* __restrict__ V,
                                              float* __restrict__ ws) {
  const int t = threadIdx.x;
  const int m0 = blockIdx.x * 64;
  __shared__ float vt_f[64][261];
  #pragma unroll
  for (int i = 0; i < 4; ++i) {
    const int ml = (t >> 4) + 16*i;
    const int mg = m0 + ml;
    #pragma unroll
    for (int j = 0; j < 4; ++j) {
      const int d = 4*(t & 15) + 64*j;
      float4 v = make_float4(0.f, 0.f, 0.f, 0.f);
      if (mg < MCOLS) v = *(const float4*)(V + (size_t)mg*DDIM + d);
      vt_f[ml][d] = v.x; vt_f[ml][d+1] = v.y; vt_f[ml][d+2] = v.z; vt_f[ml][d+3] = v.w;
    }
  }
  __syncthreads();
  unsigned short* vt = (unsigned short*)((char*)ws + WS_VT_BYTE);
  const int tl = t & 15;
  const int s = tl >> 1, hf = tl & 1;
  const int mq = 8*s + 4*hf;
  #pragma unroll
  for (int it = 0; it < 16; ++it) {
    const int d = (t >> 4) + 16*it;
    uint2 u;
    u.x = pk2(vt_f[mq+0][d], vt_f[mq+1][d]);
    u.y = pk2(vt_f[mq+2][d], vt_f[mq+3][d]);
    const int sp = s ^ (d & 7);
    *(uint2*)(vt + (size_t)d*MP + m0 + sp*8 + 4*hf) = u;
  }
}

// ---------------- staging helpers (GLL, linear dst) ----------------
static __device__ __forceinline__ void stage_k(const char* __restrict__ kb,
                                               int m0, int w, int l,
                                               unsigned short (*klds)[256]) {
  #pragma unroll
  for (int i = 0; i < 4; ++i) {
    int r = m0 + w*8 + i*2 + (l >> 5);
    r = min(r, MCOLS - 1);
    const char* g = kb + (size_t)r*512 + (l & 31)*16;
    char* dst = (char*)&klds[w*8 + i*2][0];
    GLL(g, dst);
  }
}
static __device__ __forceinline__ void stage_vt(const char* __restrict__ vtb,
                                                int m1, int w, int l,
                                                unsigned short (*vtl)[64]) {
  #pragma unroll
  for (int i = 0; i < 4; ++i) {
    const int d = w*32 + i*8 + (l >> 3);
    const int ms = min(m1 + (l & 7)*8, MP - 8);
    const char* g = vtb + ((size_t)d*MP + ms)*2;
    char* dst = (char*)&vtl[w*32 + i*8][0];
    GLL(g, dst);
  }
}

// ---------------- k2 (path B): merge chunk sums -> 1/l ----------------
template<int NSUM>
__global__ void k2_final(const float* __restrict__ out, float* __restrict__ ws) {
  const int b = blockIdx.x, t = threadIdx.x;   // 512 x 256
  float v = (t < NSUM) ? out[(size_t)t*512 + b] : 0.f;
  #pragma unroll
  for (int mk = 1; mk <= 32; mk <<= 1) v += __shfl_xor(v, mk);
  __shared__ float s2[4];
  if ((t & 63) == 0) s2[t >> 6] = v;
  __syncthreads();
  if (t == 0) ws[WS_RCPL + b] = 1.0f / (s2[0] + s2[1] + s2[2] + s2[3]);
}

// ---------------- k3a (path A): r8-exact fused attn-write + PV ----------------
__global__ __launch_bounds__(512, 4) void k3a_main(float* __restrict__ ws,
                                                   float* __restrict__ out) {
  const int bid = blockIdx.x;                 // 448: co-XCD map
  const int xg = bid & 7, i = bid >> 3;
  const int c = xg + 8*(i % 7), rb = i / 7;
  const int t = threadIdx.x, w = t >> 6, l = t & 63, q = l >> 4, ln = l & 15;
  const int ar = w & 3, h = w >> 2, l7 = ln & 7;
  __shared__ __align__(16) unsigned short klds[64][256];   // 32KB single
  __shared__ __align__(16) unsigned short vtl[256][64];    // 32KB single
  __shared__ __align__(16) unsigned short plds[64][64];    // 8KB XOR-swizzled
  const char* kb  = (const char*)ws + WS_KB_BYTE;
  const char* vtb = (const char*)ws + WS_VT_BYTE;
  const unsigned short* xb = (const unsigned short*)((const char*)ws + WS_XB_BYTE);
  const int R0 = rb*64;

  short8 xf[8];
  {
    const int row = R0 + 16*ar + ln;
    #pragma unroll
    for (int kk = 0; kk < 8; ++kk)
      xf[kk] = *(const short8*)(xb + row*DDIM + 32*kk + 8*q);
  }
  float rlq[4];
  #pragma unroll
  for (int r = 0; r < 4; ++r)
    rlq[r] = ws[WS_RCPL + R0 + 16*ar + 4*q + r];
  f32x4 apv[8];
  #pragma unroll
  for (int dx = 0; dx < 8; ++dx) { f32x4 z = {0.f,0.f,0.f,0.f}; apv[dx] = z; }
  const int d2 = 128*h;
  float* attn = out + ATTN_OFF;
  const int mbase = c*CHUNK;
  const int nt = min(NTFULL, (MCOLS - mbase + 63) >> 6);
  unsigned short* pf = &plds[0][0];

  stage_k(kb, mbase, w, l, klds);
  __syncthreads();

  for (int mt = 0; mt < nt; ++mt) {
    const int m0 = mbase + mt*64;
    stage_vt(vtb, m0, w, l, vtl);            // VT(t), overlaps QK; drains at bar1
    // ---- QK ----
    const int row0 = 32*h + ln;
    f32x4 acc[2];
    { f32x4 z = {0.f,0.f,0.f,0.f}; acc[0] = z; acc[1] = z; }
    #pragma unroll
    for (int kk = 0; kk < 8; ++kk) {
      const int sl = ((q + 4*kk) ^ l7) << 4;
      const short8 b0 = *(const short8*)((const char*)&klds[0][0] + row0*512 + sl);
      const short8 b1 = *(const short8*)((const char*)&klds[0][0] + (row0 + 16)*512 + sl);
      acc[0] = __builtin_amdgcn_mfma_f32_16x16x32_bf16(xf[kk], b0, acc[0], 0,0,0);
      acc[1] = __builtin_amdgcn_mfma_f32_16x16x32_bf16(xf[kk], b1, acc[1], 0,0,0);
    }
    const int mr0 = m0 + row0, mr1 = mr0 + 16;
    const bool ok0 = mr0 < MCOLS, ok1 = mr1 < MCOLS;
    #pragma unroll
    for (int r = 0; r < 4; ++r) {
      const int rowl = 16*ar + 4*q + r;
      const float p0v = ok0 ? __expf(acc[0][r]) : 0.f;
      const float p1v = ok1 ? __expf(acc[1][r]) : 0.f;
      float* arow = attn + (size_t)(R0 + rowl)*MCOLS;
      if (ok0) arow[mr0] = p0v*rlq[r];
      if (ok1) arow[mr1] = p1v*rlq[r];
      const int r7 = rowl & 7;
      pf[rowl*64 + ((((ln>>3) + 4*h    ) ^ r7) << 3) + (ln & 7)] = f2bfu(p0v);
      pf[rowl*64 + ((((ln>>3) + 4*h + 2) ^ r7) << 3) + (ln & 7)] = f2bfu(p1v);
    }
    __syncthreads();                         // bar1: VT staged, plds ready, klds free
    if (mt + 1 < nt) stage_k(kb, m0 + 64, w, l, klds);  // K(t+1), overlaps PV
    // ---- PV ----
    const int prow = 16*ar + ln;
    const short8 af0 = *(const short8*)(pf + prow*64 + ((q       ^ l7) << 3));
    const short8 af1 = *(const short8*)(pf + prow*64 + (((4 + q) ^ l7) << 3));
    #pragma unroll
    for (int dx = 0; dx < 8; ++dx) {
      const int R = d2 + 16*dx + ln;
      const char* vr = (const char*)&vtl[0][0] + R*128;
      const short8 bv0 = *(const short8*)(vr + ((q       ^ l7) << 4));
      const short8 bv1 = *(const short8*)(vr + (((4 + q) ^ l7) << 4));
      apv[dx] = __builtin_amdgcn_mfma_f32_16x16x32_bf16(af0, bv0, apv[dx], 0,0,0);
      apv[dx] = __builtin_amdgcn_mfma_f32_16x16x32_bf16(af1, bv1, apv[dx], 0,0,0);
    }
    __syncthreads();                         // bar2: vtl reads done, K(t+1) staged
  }

  float* part = (float*)((char*)ws + WS_PART_BYTE);
  #pragma unroll
  for (int dx = 0; dx < 8; ++dx)
    #pragma unroll
    for (int r = 0; r < 4; ++r)
      part[((size_t)c*512 + R0 + 16*ar + 4*q + r)*256 + d2 + 16*dx + ln]
        = apv[dx][r]*rlq[r];
}

// ---------------- k3b (path B fallback): direct-load, unnorm + sums ----------------
static __device__ __forceinline__ void load_xf(const float* __restrict__ x,
                                               int brow0, int q, int ln,
                                               short8 xf[2][8]) {
  #pragma unroll
  for (int as = 0; as < 2; ++as) {
    const int row = brow0 + 16*as + ln;
    #pragma unroll
    for (int kk = 0; kk < 8; ++kk) {
      const float* p = x + row*DDIM + 32*kk + 8*q;
      xf[as][kk] = pack8(*(const float4*)p, *(const float4*)(p + 4));
    }
  }
}

__global__ __launch_bounds__(512, 2) void k3b_main(const float* __restrict__ x,
                                                   const float* __restrict__ K,
                                                   float* __restrict__ ws,
                                                   float* __restrict__ out) {
  const int bid = blockIdx.x;                 // 224 = 56 chunks * 4 rb
  const int c = bid >> 2, rb = bid & 3;
  const int t = threadIdx.x, w = t >> 6, l = t & 63, q = l >> 4, ln = l & 15;
  const int h = w & 1, rg = w >> 1;
  __shared__ __align__(16) unsigned short plds[2][128][72];
  const int R0 = rb*128;
  short8 xf[2][8];
  const int brow0 = R0 + 32*rg;
  load_xf(x, brow0, q, ln, xf);
  float rxn[2][4];
  #pragma unroll
  for (int as = 0; as < 2; ++as)
    #pragma unroll
    for (int r = 0; r < 4; ++r)
      rxn[as][r] = ws[WS_RXN + brow0 + 16*as + 4*q + r];
  float lpr[2][4] = {{0.f,0.f,0.f,0.f},{0.f,0.f,0.f,0.f}};
  f32x4 apv[2][8];
  #pragma unroll
  for (int bs = 0; bs < 2; ++bs)
    #pragma unroll
    for (int dx = 0; dx < 8; ++dx) { f32x4 z = {0.f,0.f,0.f,0.f}; apv[bs][dx] = z; }
  const int b2 = 32*(w & 3), d2 = 128*(w >> 2);
  const unsigned short* vt = (const unsigned short*)((const char*)ws + WS_VT_BYTE);
  const float* rknw = ws + WS_RKN;
  float* attn = out + ATTN_OFF;
  const int mbase = c*CHUNK;
  const int nt = min(NTFULL, (MCOLS - mbase + 63) >> 6);
  const int l7 = ln & 7;

  for (int mt = 0; mt < nt; ++mt) {
    const int m0 = mbase + mt*64;
    const int mr0 = m0 + 32*h + ln, mr1 = mr0 + 16;
    const int kr0 = min(mr0, MCOLS-1), kr1 = min(mr1, MCOLS-1);
    f32x4 acc[2][2];
    #pragma unroll
    for (int as = 0; as < 2; ++as)
      #pragma unroll
      for (int mm = 0; mm < 2; ++mm) { f32x4 z = {0.f,0.f,0.f,0.f}; acc[as][mm] = z; }
    const float* p0 = K + (size_t)kr0*DDIM + 8*q;
    const float* p1 = K + (size_t)kr1*DDIM + 8*q;
    #pragma unroll
    for (int kk = 0; kk < 8; ++kk) {
      const short8 b0 = pack8(*(const float4*)(p0 + 32*kk), *(const float4*)(p0 + 32*kk + 4));
      const short8 b1 = pack8(*(const float4*)(p1 + 32*kk), *(const float4*)(p1 + 32*kk + 4));
      acc[0][0] = __builtin_amdgcn_mfma_f32_16x16x32_bf16(xf[0][kk], b0, acc[0][0], 0,0,0);
      acc[0][1] = __builtin_amdgcn_mfma_f32_16x16x32_bf16(xf[0][kk], b1, acc[0][1], 0,0,0);
      acc[1][0] = __builtin_amdgcn_mfma_f32_16x16x32_bf16(xf[1][kk], b0, acc[1][0], 0,0,0);
      acc[1][1] = __builtin_amdgcn_mfma_f32_16x16x32_bf16(xf[1][kk], b1, acc[1][1], 0,0,0);
    }
    const float rk0 = rknw[kr0], rk1 = rknw[kr1];
    const bool ok0 = mr0 < MCOLS, ok1 = mr1 < MCOLS;
    #pragma unroll
    for (int as = 0; as < 2; ++as)
      #pragma unroll
      for (int r = 0; r < 4; ++r) {
        const int rowl = 32*rg + 16*as + 4*q + r;
        const float p0v = ok0 ? __expf(acc[as][0][r]*rxn[as][r]*rk0) : 0.f;
        const float p1v = ok1 ? __expf(acc[as][1][r]*rxn[as][r]*rk1) : 0.f;
        float* arow = attn + (size_t)(R0 + rowl)*MCOLS;
        if (ok0) arow[mr0] = p0v;
        if (ok1) arow[mr1] = p1v;
        lpr[as][r] += p0v + p1v;
        plds[mt & 1][rowl][32*h + ln]      = f2bfu(p0v);
        plds[mt & 1][rowl][32*h + 16 + ln] = f2bfu(p1v);
      }
    __syncthreads();
    const unsigned short (*pb)[72] = plds[mt & 1];
    const short8 af00 = *(const short8*)&pb[b2 + ln][8*q];
    const short8 af01 = *(const short8*)&pb[b2 + ln][32 + 8*q];
    const short8 af10 = *(const short8*)&pb[b2 + 16 + ln][8*q];
    const short8 af11 = *(const short8*)&pb[b2 + 16 + ln][32 + 8*q];
    #pragma unroll
    for (int dx = 0; dx < 8; ++dx) {
      const int R = d2 + 16*dx + ln;
      const size_t rbase = (size_t)R*MP + m0;
      const short8 bv0 = *(const short8*)(vt + rbase + ((q     ^ (R & 7)) << 3));
      const short8 bv1 = *(const short8*)(vt + rbase + (((4+q) ^ (R & 7)) << 3));
      apv[0][dx] = __builtin_amdgcn_mfma_f32_16x16x32_bf16(af00, bv0, apv[0][dx], 0,0,0);
      apv[0][dx] = __builtin_amdgcn_mfma_f32_16x16x32_bf16(af01, bv1, apv[0][dx], 0,0,0);
      apv[1][dx] = __builtin_amdgcn_mfma_f32_16x16x32_bf16(af10, bv0, apv[1][dx], 0,0,0);
      apv[1][dx] = __builtin_amdgcn_mfma_f32_16x16x32_bf16(af11, bv1, apv[1][dx], 0,0,0);
    }
  }

  #pragma unroll
  for (int as = 0; as < 2; ++as)
    #pragma unroll
    for (int r = 0; r < 4; ++r) {
      float s = lpr[as][r];
      s += __shfl_xor(s, 1); s += __shfl_xor(s, 2);
      s += __shfl_xor(s, 4); s += __shfl_xor(s, 8);
      if (ln == 0)
        out[(size_t)(c*2 + h)*512 + brow0 + 16*as + 4*q + r] = s;
    }
  float* part = (float*)((char*)ws + WS_PART_BYTE);
  #pragma unroll
  for (int bs = 0; bs < 2; ++bs)
    #pragma unroll
    for (int dx = 0; dx < 8; ++dx)
      #pragma unroll
      for (int r = 0; r < 4; ++r)
        part[((size_t)c*512 + R0 + b2 + 16*bs + 4*q + r)*256 + d2 + 16*dx + ln]
          = apv[bs][dx][r];
}

// ---------------- k4: reduce retrieved partials ----------------
template<bool NORM>
__global__ void k4_red(const float* __restrict__ ws, float* __restrict__ out) {
  const int b = blockIdx.x, t = threadIdx.x;
  const float* part = (const float*)((const char*)ws + WS_PART_BYTE);
  float acc = 0.f;
  for (int cc = 0; cc < NSLOT; ++cc)
    acc += part[((size_t)cc*512 + b)*256 + t];
  if (!NORM) acc *= ws[WS_RCPL + b];
  out[b*DDIM + t] = acc;
}

// ---------------- k5 (path B): rescale attn by 1/l (f32x4) ----------------
__global__ void k5_scale(const float* __restrict__ ws, float* __restrict__ out) {
  const int row = blockIdx.y;
  const int i4 = blockIdx.x*256 + threadIdx.x;
  if (i4 >= MCOLS/4) return;
  const float s = ws[WS_RCPL + row];
  float4* p = (float4*)(out + ATTN_OFF + (size_t)row*MCOLS) + i4;
  float4 v = *p;
  v.x *= s; v.y *= s; v.z *= s; v.w *= s;
  *p = v;
}

extern "C" void kernel_launch(void* const* d_in, const int* in_sizes, int n_in,
                              void* d_out, int out_size, void* d_ws, size_t ws_size,
                              hipStream_t stream) {
  const float* x = (const float*)d_in[0];
  const float* K = (const float*)d_in[1];
  const float* V = (const float*)d_in[2];
  float* out = (float*)d_out;
  float* ws  = (float*)d_ws;
  const bool useKB = ws_size >= WS_KB_END;

  k0_xn<<<512, 256, 0, stream>>>(x, ws);
  if (useKB) {                               // Path A
    kA_fused<<<NCHA, 512, 0, stream>>>(K, ws, out);
    k0b_tr<<<MP/64, 256, 0, stream>>>(V, ws);
    k2A_final<<<512, 256, 0, stream>>>(out, ws);
    k3a_main<<<448, 512, 0, stream>>>(ws, out);
    k4_red<true><<<512, 256, 0, stream>>>(ws, out);
  } else {                                   // Path B
    k0c_kn<<<1563, 256, 0, stream>>>(K, ws);
    k0b_tr<<<MP/64, 256, 0, stream>>>(V, ws);
    k3b_main<<<224, 512, 0, stream>>>(x, K, ws, out);
    k2_final<112><<<512, 256, 0, stream>>>(out, ws);
    k5_scale<<<dim3((MCOLS/4 + 255)/256, 512), 256, 0, stream>>>(ws, out);
    k4_red<false><<<512, 256, 0, stream>>>(ws, out);
  }
}

// Round 10
// 282.629 us; speedup vs baseline: 1.2535x; 1.2535x over previous
//
#include <hip/hip_runtime.h>
#include <hip/hip_bf16.h>

// GroupNLMSMemory: B=512, D=256, M=100000
// out = [retrieved 512x256 | attn 512x100000] (f32)
// r10: r8 pipeline; k3a rebuilt with raw s_barrier + counted vmcnt (T4):
//   issue order per tile puts must-wait GLL loads OLDER than store-acks in the
//   per-wave VMEM FIFO, so barriers never drain fresh stores. pf32 (f32, XOR-
//   swizzled) replaces plds: PV converts to bf16; attn stores become coalesced
//   float4 rows. LDS 80KB -> still 2 blk/CU.
// Path A (ws >= 135.4MB): k0,k0c<KB>,k0b -> k1b32 -> k2<256> -> k3a -> k4<true>
// Path B fallback: k0,k0c<false>,k0b -> k3b -> k2<112> -> k5,k4<false>

#define MCOLS 100000
#define MP    100032
#define DDIM  256
#define CHUNK 1792                 // k3: 28 tiles of 64
#define NTFULL 28
#define NCHUNK 56
#define NSLOT 56
#define CHUNK1 832                 // k1b: 26 tiles of 32
#define NT1   26
#define ATTN_OFF 131072
#define WS_RXN  0
#define WS_RKN  512
#define WS_RCPL 100512
#define WS_XB_BYTE   409600ull
#define WS_VT_BYTE   1048576ull
#define WS_PART_BYTE 52264960ull
#define WS_KB_BYTE   84246528ull
#define WS_KB_END    (WS_KB_BYTE + 2ull*(size_t)MCOLS*DDIM) // 135,446,528

#define GLL(g, l) __builtin_amdgcn_global_load_lds( \
    (const __attribute__((address_space(1))) void*)(g), \
    (__attribute__((address_space(3))) void*)(l), 16, 0, 0)

typedef short short8 __attribute__((ext_vector_type(8)));
typedef float f32x4  __attribute__((ext_vector_type(4)));

static __device__ __forceinline__ unsigned short f2bfu(float f) {
  union { __hip_bfloat16 h; unsigned short u; } cv;
  cv.h = __float2bfloat16(f);
  return cv.u;
}
static __device__ __forceinline__ unsigned int pk2(float a, float b) {
  return (unsigned int)f2bfu(a) | ((unsigned int)f2bfu(b) << 16);
}
static __device__ __forceinline__ short8 pack8(float4 a, float4 b) {
  short8 r;
  r[0] = (short)f2bfu(a.x); r[1] = (short)f2bfu(a.y);
  r[2] = (short)f2bfu(a.z); r[3] = (short)f2bfu(a.w);
  r[4] = (short)f2bfu(b.x); r[5] = (short)f2bfu(b.y);
  r[6] = (short)f2bfu(b.z); r[7] = (short)f2bfu(b.w);
  return r;
}

// ---------------- k0: x norms -> rxn + xb = bf16(10*x/|x|) ----------------
__global__ void k0_xn(const float* __restrict__ x, float* __restrict__ ws) {
  const int b = blockIdx.x, t = threadIdx.x;
  const float v = x[b*DDIM + t];
  float s = v*v;
  #pragma unroll
  for (int mk = 1; mk <= 32; mk <<= 1) s += __shfl_xor(s, mk);
  __shared__ float ps[4];
  if ((t & 63) == 0) ps[t >> 6] = s;
  __syncthreads();
  const float tot = ps[0] + ps[1] + ps[2] + ps[3];
  const float r10 = 10.0f / fmaxf(sqrtf(tot), 1e-12f);
  if (t == 0) ws[WS_RXN + b] = r10;
  unsigned short* xbp = (unsigned short*)((char*)ws + WS_XB_BYTE);
  xbp[b*DDIM + t] = f2bfu(v * r10);
}

// ---------------- k0c: K norms (+ normalized swizzled Kbf16) ----------------
template<bool WRITEKB>
__global__ __launch_bounds__(256) void k0c_kn(const float* __restrict__ K,
                                              float* __restrict__ ws) {
  const int t = threadIdx.x;
  const int mg = blockIdx.x*64 + (t >> 2);
  const int qq = t & 3;
  if (mg >= MCOLS) return;
  const float* kp = K + (size_t)mg*DDIM + 64*qq;
  float4 buf[16];
  float ss = 0.f;
  #pragma unroll
  for (int j = 0; j < 16; ++j) {
    buf[j] = *(const float4*)(kp + 4*j);
    ss += buf[j].x*buf[j].x + buf[j].y*buf[j].y + buf[j].z*buf[j].z + buf[j].w*buf[j].w;
  }
  ss += __shfl_xor(ss, 1); ss += __shfl_xor(ss, 2);
  const float rk = 1.0f / fmaxf(sqrtf(ss), 1e-12f);
  if (qq == 0) ws[WS_RKN + mg] = rk;
  if (WRITEKB) {
    unsigned int* kb = (unsigned int*)((char*)ws + WS_KB_BYTE);
    #pragma unroll
    for (int j = 0; j < 8; ++j) {
      const float4 a = buf[2*j], b2 = buf[2*j+1];
      uint4 u;
      u.x = pk2(a.x*rk, a.y*rk);  u.y = pk2(a.z*rk, a.w*rk);
      u.z = pk2(b2.x*rk, b2.y*rk); u.w = pk2(b2.z*rk, b2.w*rk);
      const int slot = (8*qq + j) ^ (mg & 7);   // 16B-slot XOR swizzle
      *(uint4*)(kb + (size_t)mg*128 + slot*4) = u;
    }
  }
}

// ---------------- k0b: V -> VT bf16 [256][MP], slot^(d&7) swizzled ----------------
__global__ __launch_bounds__(256) void k0b_tr(const float* __restrict__ V,
                                              float* __restrict__ ws) {
  const int t = threadIdx.x;
  const int m0 = blockIdx.x * 64;
  __shared__ float vt_f[64][261];
  #pragma unroll
  for (int i = 0; i < 4; ++i) {
    const int ml = (t >> 4) + 16*i;
    const int mg = m0 + ml;
    #pragma unroll
    for (int j = 0; j < 4; ++j) {
      const int d = 4*(t & 15) + 64*j;
      float4 v = make_float4(0.f, 0.f, 0.f, 0.f);
      if (mg < MCOLS) v = *(const float4*)(V + (size_t)mg*DDIM + d);
      vt_f[ml][d] = v.x; vt_f[ml][d+1] = v.y; vt_f[ml][d+2] = v.z; vt_f[ml][d+3] = v.w;
    }
  }
  __syncthreads();
  unsigned short* vt = (unsigned short*)((char*)ws + WS_VT_BYTE);
  const int tl = t & 15;
  const int s = tl >> 1, hf = tl & 1;
  const int mq = 8*s + 4*hf;
  #pragma unroll
  for (int it = 0; it < 16; ++it) {
    const int d = (t >> 4) + 16*it;
    uint2 u;
    u.x = pk2(vt_f[mq+0][d], vt_f[mq+1][d]);
    u.y = pk2(vt_f[mq+2][d], vt_f[mq+3][d]);
    const int sp = s ^ (d & 7);
    *(uint2*)(vt + (size_t)d*MP + m0 + sp*8 + 4*hf) = u;
  }
}

// ---------------- staging helpers (GLL, linear dst) ----------------
static __device__ __forceinline__ void stage_k(const char* __restrict__ kb,
                                               int m0, int w, int l,
                                               unsigned short (*klds)[256]) {
  #pragma unroll
  for (int i = 0; i < 4; ++i) {
    int r = m0 + w*8 + i*2 + (l >> 5);
    r = min(r, MCOLS - 1);
    const char* g = kb + (size_t)r*512 + (l & 31)*16;
    char* dst = (char*)&klds[w*8 + i*2][0];
    GLL(g, dst);
  }
}
static __device__ __forceinline__ void stage_k32(const char* __restrict__ kb,
                                                 int m0, int w, int l,
                                                 unsigned short (*klds)[256]) {
  #pragma unroll
  for (int i = 0; i < 2; ++i) {
    int r = m0 + w*4 + i*2 + (l >> 5);
    r = min(r, MCOLS - 1);
    const char* g = kb + (size_t)r*512 + (l & 31)*16;
    char* dst = (char*)&klds[w*4 + i*2][0];
    GLL(g, dst);
  }
}
static __device__ __forceinline__ void stage_vt(const char* __restrict__ vtb,
                                                int m1, int w, int l,
                                                unsigned short (*vtl)[64]) {
  #pragma unroll
  for (int i = 0; i < 4; ++i) {
    const int d = w*32 + i*8 + (l >> 3);
    const int ms = min(m1 + (l & 7)*8, MP - 8);
    const char* g = vtb + ((size_t)d*MP + ms)*2;
    char* dst = (char*)&vtl[w*32 + i*8][0];
    GLL(g, dst);
  }
}

// ---------------- k1b32: sum-of-exp, 32-row tiles, 4 blk/CU (r8-exact) ----------------
__global__ __launch_bounds__(512, 8) void k1b_sum(const float* __restrict__ ws,
                                                  float* __restrict__ out) {
  const int bid = blockIdx.x;                 // 1024 = 8 xg * 16 cg * 8 rb
  const int xg = bid & 7, i = bid >> 3;
  const int c = xg + 8*(i & 15), rb = i >> 4;
  const int t = threadIdx.x, w = t >> 6, l = t & 63, q = l >> 4, ln = l & 15;
  const int ar = w & 3, h = w >> 2, l7 = ln & 7;
  __shared__ __align__(16) unsigned short klds2[2][32][256];
  const char* kb = (const char*)ws + WS_KB_BYTE;
  const unsigned short* xb = (const unsigned short*)((const char*)ws + WS_XB_BYTE);
  const int R0 = rb*64;

  short8 xf[8];
  {
    const int row = R0 + 16*ar + ln;
    #pragma unroll
    for (int kk = 0; kk < 8; ++kk)
      xf[kk] = *(const short8*)(xb + row*DDIM + 32*kk + 8*q);
  }
  float lpr[4] = {0.f,0.f,0.f,0.f};
  const int mbase = c*CHUNK1;
  const int rem = MCOLS - mbase;
  const int nt = rem <= 0 ? 0 : min(NT1, (rem + 31) >> 5);

  if (nt > 0) {
    stage_k32(kb, mbase, w, l, klds2[0]);
    __syncthreads();
    for (int mt = 0; mt < nt; ++mt) {
      const int cur = mt & 1;
      const int m0 = mbase + mt*32;
      if (mt + 1 < nt) stage_k32(kb, m0 + 32, w, l, klds2[cur ^ 1]);
      const char* kbase = (const char*)&klds2[cur][0][0];
      const int row0 = 16*h + ln;
      f32x4 acc = {0.f,0.f,0.f,0.f};
      #pragma unroll
      for (int kk = 0; kk < 8; ++kk) {
        const int sl = ((q + 4*kk) ^ l7) << 4;
        const short8 b0 = *(const short8*)(kbase + row0*512 + sl);
        acc = __builtin_amdgcn_mfma_f32_16x16x32_bf16(xf[kk], b0, acc, 0,0,0);
      }
      const int mr = m0 + row0;
      const bool ok = mr < MCOLS;
      #pragma unroll
      for (int r = 0; r < 4; ++r)
        lpr[r] += ok ? __expf(acc[r]) : 0.f;
      __syncthreads();
    }
  }
  #pragma unroll
  for (int r = 0; r < 4; ++r) {
    float s = lpr[r];
    s += __shfl_xor(s, 1); s += __shfl_xor(s, 2);
    s += __shfl_xor(s, 4); s += __shfl_xor(s, 8);
    if (ln == 0)
      out[(size_t)(c*2 + h)*512 + R0 + 16*ar + 4*q + r] = s;
  }
}

// ---------------- k2: merge chunk sums -> 1/l ----------------
template<int NSUM>
__global__ void k2_final(const float* __restrict__ out, float* __restrict__ ws) {
  const int b = blockIdx.x, t = threadIdx.x;   // 512 x 256
  float v = (t < NSUM) ? out[(size_t)t*512 + b] : 0.f;
  #pragma unroll
  for (int mk = 1; mk <= 32; mk <<= 1) v += __shfl_xor(v, mk);
  __shared__ float s2[4];
  if ((t & 63) == 0) s2[t >> 6] = v;
  __syncthreads();
  if (t == 0) ws[WS_RCPL + b] = 1.0f / (s2[0] + s2[1] + s2[2] + s2[3]);
}

// ---------------- k3a (path A): counted-vmcnt pipelined fused kernel ----------------
__global__ __launch_bounds__(512, 4) void k3a_main(float* __restrict__ ws,
                                                   float* __restrict__ out) {
  const int bid = blockIdx.x;                 // 448: co-XCD map
  const int xg = bid & 7, i = bid >> 3;
  const int c = xg + 8*(i % 7), rb = i / 7;
  const int t = threadIdx.x, w = t >> 6, l = t & 63, q = l >> 4, ln = l & 15;
  const int ar = w & 3, h = w >> 2, l7 = ln & 7;
  __shared__ __align__(16) unsigned short klds[64][256];   // 32KB
  __shared__ __align__(16) unsigned short vtl[256][64];    // 32KB
  __shared__ __align__(16) float pf32[64][64];             // 16KB, 16B-XOR swz
  const char* kb  = (const char*)ws + WS_KB_BYTE;
  const char* vtb = (const char*)ws + WS_VT_BYTE;
  const unsigned short* xb = (const unsigned short*)((const char*)ws + WS_XB_BYTE);
  const int R0 = rb*64;

  short8 xf[8];
  {
    const int row = R0 + 16*ar + ln;
    #pragma unroll
    for (int kk = 0; kk < 8; ++kk)
      xf[kk] = *(const short8*)(xb + row*DDIM + 32*kk + 8*q);
  }
  float rlq[4];                                // own rows (partials scale)
  #pragma unroll
  for (int r = 0; r < 4; ++r)
    rlq[r] = ws[WS_RCPL + R0 + 16*ar + 4*q + r];
  const int sr0 = 8*w + (l >> 4);              // store-path rows
  const float srlq0 = ws[WS_RCPL + R0 + sr0];
  const float srlq1 = ws[WS_RCPL + R0 + sr0 + 4];
  f32x4 apv[8];
  #pragma unroll
  for (int dx = 0; dx < 8; ++dx) { f32x4 z = {0.f,0.f,0.f,0.f}; apv[dx] = z; }
  const int d2 = 128*h;
  float* attn = out + ATTN_OFF;
  const int mbase = c*CHUNK;
  const int nt = min(NTFULL, (MCOLS - mbase + 63) >> 6);

  stage_k(kb, mbase, w, l, klds);
  stage_vt(vtb, mbase, w, l, vtl);
  asm volatile("s_waitcnt vmcnt(0) lgkmcnt(0)" ::: "memory");
  __builtin_amdgcn_sched_barrier(0);
  __builtin_amdgcn_s_barrier();
  __builtin_amdgcn_sched_barrier(0);

  for (int mt = 0; mt < nt; ++mt) {
    const int m0 = mbase + mt*64;
    // ---- QK (reads klds = K(t)) ----
    const int row0 = 32*h + ln;
    f32x4 acc[2];
    { f32x4 z = {0.f,0.f,0.f,0.f}; acc[0] = z; acc[1] = z; }
    #pragma unroll
    for (int kk = 0; kk < 8; ++kk) {
      const int sl = ((q + 4*kk) ^ l7) << 4;
      const short8 b0 = *(const short8*)((const char*)&klds[0][0] + row0*512 + sl);
      const short8 b1 = *(const short8*)((const char*)&klds[0][0] + (row0 + 16)*512 + sl);
      acc[0] = __builtin_amdgcn_mfma_f32_16x16x32_bf16(xf[kk], b0, acc[0], 0,0,0);
      acc[1] = __builtin_amdgcn_mfma_f32_16x16x32_bf16(xf[kk], b1, acc[1], 0,0,0);
    }
    const int mr0 = m0 + row0, mr1 = mr0 + 16;
    const bool ok0 = mr0 < MCOLS, ok1 = mr1 < MCOLS;
    #pragma unroll
    for (int r = 0; r < 4; ++r) {
      const int rowl = 16*ar + 4*q + r;
      const float p0v = ok0 ? __expf(acc[0][r]) : 0.f;
      const float p1v = ok1 ? __expf(acc[1][r]) : 0.f;
      const int r7 = rowl & 7;
      pf32[rowl][(((8*h + (ln >> 2))    ) ^ r7)*4 + (ln & 3)] = p0v;
      pf32[rowl][(((8*h + 4 + (ln >> 2))) ^ r7)*4 + (ln & 3)] = p1v;
    }
    // bar1: VT(t) landed (issued last iter; QK covered latency); pf32 visible.
    asm volatile("s_waitcnt vmcnt(0) lgkmcnt(0)" ::: "memory");
    __builtin_amdgcn_sched_barrier(0);
    __builtin_amdgcn_s_barrier();
    __builtin_amdgcn_sched_barrier(0);
    // K(t+1) FIRST in FIFO (must-wait at bar2)...
    if (mt + 1 < nt) stage_k(kb, m0 + 64, w, l, klds);
    __builtin_amdgcn_sched_barrier(0);
    // ...then attn stores (never waited on before their acks age out)
    {
      const int c4 = l & 15;
      const bool cok = (m0 + 4*c4) < MCOLS;    // MCOLS%4==0 -> whole float4
      const int rowA = sr0, rowB = sr0 + 4;
      const float4 va = *(const float4*)&pf32[rowA][(c4 ^ (rowA & 7))*4];
      const float4 vb = *(const float4*)&pf32[rowB][(c4 ^ (rowB & 7))*4];
      if (cok) {
        float4 o;
        o.x = va.x*srlq0; o.y = va.y*srlq0; o.z = va.z*srlq0; o.w = va.w*srlq0;
        *(float4*)(attn + (size_t)(R0 + rowA)*MCOLS + m0 + 4*c4) = o;
        o.x = vb.x*srlq1; o.y = vb.y*srlq1; o.z = vb.z*srlq1; o.w = vb.w*srlq1;
        *(float4*)(attn + (size_t)(R0 + rowB)*MCOLS + m0 + 4*c4) = o;
      }
    }
    // ---- PV (reads vtl = VT(t), pf32 -> bf16) ----
    short8 af0, af1;
    {
      const int prow = 16*ar + ln, p7 = prow & 7;
      const float4 a0 = *(const float4*)&pf32[prow][((2*q    ) ^ p7)*4];
      const float4 a1 = *(const float4*)&pf32[prow][((2*q + 1) ^ p7)*4];
      const float4 a2 = *(const float4*)&pf32[prow][((8 + 2*q) ^ p7)*4];
      const float4 a3 = *(const float4*)&pf32[prow][((9 + 2*q) ^ p7)*4];
      af0 = pack8(a0, a1);
      af1 = pack8(a2, a3);
    }
    #pragma unroll
    for (int dx = 0; dx < 8; ++dx) {
      const int R = d2 + 16*dx + ln;
      const char* vr = (const char*)&vtl[0][0] + R*128;
      const short8 bv0 = *(const short8*)(vr + ((q       ^ l7) << 4));
      const short8 bv1 = *(const short8*)(vr + (((4 + q) ^ l7) << 4));
      apv[dx] = __builtin_amdgcn_mfma_f32_16x16x32_bf16(af0, bv0, apv[dx], 0,0,0);
      apv[dx] = __builtin_amdgcn_mfma_f32_16x16x32_bf16(af1, bv1, apv[dx], 0,0,0);
    }
    // bar_pv: all waves done reading vtl/pf32 (reads consumed in-wave).
    __builtin_amdgcn_sched_barrier(0);
    __builtin_amdgcn_s_barrier();
    __builtin_amdgcn_sched_barrier(0);
    if (mt + 1 < nt) stage_vt(vtb, m0 + 64, w, l, vtl);
    // bar2: need K(t+1) done (oldest 4 in FIFO); VT4+stores may stay in flight.
    asm volatile("s_waitcnt vmcnt(6)" ::: "memory");
    __builtin_amdgcn_sched_barrier(0);
    __builtin_amdgcn_s_barrier();
    __builtin_amdgcn_sched_barrier(0);
  }

  float* part = (float*)((char*)ws + WS_PART_BYTE);
  #pragma unroll
  for (int dx = 0; dx < 8; ++dx)
    #pragma unroll
    for (int r = 0; r < 4; ++r)
      part[((size_t)c*512 + R0 + 16*ar + 4*q + r)*256 + d2 + 16*dx + ln]
        = apv[dx][r]*rlq[r];
}

// ---------------- k3b (path B fallback): direct-load, unnorm + sums ----------------
static __device__ __forceinline__ void load_xf(const float* __restrict__ x,
                                               int brow0, int q, int ln,
                                               short8 xf[2][8]) {
  #pragma unroll
  for (int as = 0; as < 2; ++as) {
    const int row = brow0 + 16*as + ln;
    #pragma unroll
    for (int kk = 0; kk < 8; ++kk) {
      const float* p = x + row*DDIM + 32*kk + 8*q;
      xf[as][kk] = pack8(*(const float4*)p, *(const float4*)(p + 4));
    }
  }
}

__global__ __launch_bounds__(512, 2) void k3b_main(const float* __restrict__ x,
                                                   const float* __restrict__ K,
                                                   float* __restrict__ ws,
                                                   float* __restrict__ out) {
  const int bid = blockIdx.x;                 // 224 = 56 chunks * 4 rb
  const int c = bid >> 2, rb = bid & 3;
  const int t = threadIdx.x, w = t >> 6, l = t & 63, q = l >> 4, ln = l & 15;
  const int h = w & 1, rg = w >> 1;
  __shared__ __align__(16) unsigned short plds[2][128][72];
  const int R0 = rb*128;
  short8 xf[2][8];
  const int brow0 = R0 + 32*rg;
  load_xf(x, brow0, q, ln, xf);
  float rxn[2][4];
  #pragma unroll
  for (int as = 0; as < 2; ++as)
    #pragma unroll
    for (int r = 0; r < 4; ++r)
      rxn[as][r] = ws[WS_RXN + brow0 + 16*as + 4*q + r];
  float lpr[2][4] = {{0.f,0.f,0.f,0.f},{0.f,0.f,0.f,0.f}};
  f32x4 apv[2][8];
  #pragma unroll
  for (int bs = 0; bs < 2; ++bs)
    #pragma unroll
    for (int dx = 0; dx < 8; ++dx) { f32x4 z = {0.f,0.f,0.f,0.f}; apv[bs][dx] = z; }
  const int b2 = 32*(w & 3), d2 = 128*(w >> 2);
  const unsigned short* vt = (const unsigned short*)((const char*)ws + WS_VT_BYTE);
  const float* rknw = ws + WS_RKN;
  float* attn = out + ATTN_OFF;
  const int mbase = c*CHUNK;
  const int nt = min(NTFULL, (MCOLS - mbase + 63) >> 6);
  const int l7 = ln & 7;

  for (int mt = 0; mt < nt; ++mt) {
    const int m0 = mbase + mt*64;
    const int mr0 = m0 + 32*h + ln, mr1 = mr0 + 16;
    const int kr0 = min(mr0, MCOLS-1), kr1 = min(mr1, MCOLS-1);
    f32x4 acc[2][2];
    #pragma unroll
    for (int as = 0; as < 2; ++as)
      #pragma unroll
      for (int mm = 0; mm < 2; ++mm) { f32x4 z = {0.f,0.f,0.f,0.f}; acc[as][mm] = z; }
    const float* p0 = K + (size_t)kr0*DDIM + 8*q;
    const float* p1 = K + (size_t)kr1*DDIM + 8*q;
    #pragma unroll
    for (int kk = 0; kk < 8; ++kk) {
      const short8 b0 = pack8(*(const float4*)(p0 + 32*kk), *(const float4*)(p0 + 32*kk + 4));
      const short8 b1 = pack8(*(const float4*)(p1 + 32*kk), *(const float4*)(p1 + 32*kk + 4));
      acc[0][0] = __builtin_amdgcn_mfma_f32_16x16x32_bf16(xf[0][kk], b0, acc[0][0], 0,0,0);
      acc[0][1] = __builtin_amdgcn_mfma_f32_16x16x32_bf16(xf[0][kk], b1, acc[0][1], 0,0,0);
      acc[1][0] = __builtin_amdgcn_mfma_f32_16x16x32_bf16(xf[1][kk], b0, acc[1][0], 0,0,0);
      acc[1][1] = __builtin_amdgcn_mfma_f32_16x16x32_bf16(xf[1][kk], b1, acc[1][1], 0,0,0);
    }
    const float rk0 = rknw[kr0], rk1 = rknw[kr1];
    const bool ok0 = mr0 < MCOLS, ok1 = mr1 < MCOLS;
    #pragma unroll
    for (int as = 0; as < 2; ++as)
      #pragma unroll
      for (int r = 0; r < 4; ++r) {
        const int rowl = 32*rg + 16*as + 4*q + r;
        const float p0v = ok0 ? __expf(acc[as][0][r]*rxn[as][r]*rk0) : 0.f;
        const float p1v = ok1 ? __expf(acc[as][1][r]*rxn[as][r]*rk1) : 0.f;
        float* arow = attn + (size_t)(R0 + rowl)*MCOLS;
        if (ok0) arow[mr0] = p0v;
        if (ok1) arow[mr1] = p1v;
        lpr[as][r] += p0v + p1v;
        plds[mt & 1][rowl][32*h + ln]      = f2bfu(p0v);
        plds[mt & 1][rowl][32*h + 16 + ln] = f2bfu(p1v);
      }
    __syncthreads();
    const unsigned short (*pb)[72] = plds[mt & 1];
    const short8 af00 = *(const short8*)&pb[b2 + ln][8*q];
    const short8 af01 = *(const short8*)&pb[b2 + ln][32 + 8*q];
    const short8 af10 = *(const short8*)&pb[b2 + 16 + ln][8*q];
    const short8 af11 = *(const short8*)&pb[b2 + 16 + ln][32 + 8*q];
    #pragma unroll
    for (int dx = 0; dx < 8; ++dx) {
      const int R = d2 + 16*dx + ln;
      const size_t rbase = (size_t)R*MP + m0;
      const short8 bv0 = *(const short8*)(vt + rbase + ((q     ^ (R & 7)) << 3));
      const short8 bv1 = *(const short8*)(vt + rbase + (((4+q) ^ (R & 7)) << 3));
      apv[0][dx] = __builtin_amdgcn_mfma_f32_16x16x32_bf16(af00, bv0, apv[0][dx], 0,0,0);
      apv[0][dx] = __builtin_amdgcn_mfma_f32_16x16x32_bf16(af01, bv1, apv[0][dx], 0,0,0);
      apv[1][dx] = __builtin_amdgcn_mfma_f32_16x16x32_bf16(af10, bv0, apv[1][dx], 0,0,0);
      apv[1][dx] = __builtin_amdgcn_mfma_f32_16x16x32_bf16(af11, bv1, apv[1][dx], 0,0,0);
    }
  }

  #pragma unroll
  for (int as = 0; as < 2; ++as)
    #pragma unroll
    for (int r = 0; r < 4; ++r) {
      float s = lpr[as][r];
      s += __shfl_xor(s, 1); s += __shfl_xor(s, 2);
      s += __shfl_xor(s, 4); s += __shfl_xor(s, 8);
      if (ln == 0)
        out[(size_t)(c*2 + h)*512 + brow0 + 16*as + 4*q + r] = s;
    }
  float* part = (float*)((char*)ws + WS_PART_BYTE);
  #pragma unroll
  for (int bs = 0; bs < 2; ++bs)
    #pragma unroll
    for (int dx = 0; dx < 8; ++dx)
      #pragma unroll
      for (int r = 0; r < 4; ++r)
        part[((size_t)c*512 + R0 + b2 + 16*bs + 4*q + r)*256 + d2 + 16*dx + ln]
          = apv[bs][dx][r];
}

// ---------------- k4: reduce retrieved partials ----------------
template<bool NORM>
__global__ void k4_red(const float* __restrict__ ws, float* __restrict__ out) {
  const int b = blockIdx.x, t = threadIdx.x;
  const float* part = (const float*)((const char*)ws + WS_PART_BYTE);
  float acc = 0.f;
  for (int cc = 0; cc < NSLOT; ++cc)
    acc += part[((size_t)cc*512 + b)*256 + t];
  if (!NORM) acc *= ws[WS_RCPL + b];
  out[b*DDIM + t] = acc;
}

// ---------------- k5 (path B): rescale attn by 1/l (f32x4) ----------------
__global__ void k5_scale(const float* __restrict__ ws, float* __restrict__ out) {
  const int row = blockIdx.y;
  const int i4 = blockIdx.x*256 + threadIdx.x;
  if (i4 >= MCOLS/4) return;
  const float s = ws[WS_RCPL + row];
  float4* p = (float4*)(out + ATTN_OFF + (size_t)row*MCOLS) + i4;
  float4 v = *p;
  v.x *= s; v.y *= s; v.z *= s; v.w *= s;
  *p = v;
}

extern "C" void kernel_launch(void* const* d_in, const int* in_sizes, int n_in,
                              void* d_out, int out_size, void* d_ws, size_t ws_size,
                              hipStream_t stream) {
  const float* x = (const float*)d_in[0];
  const float* K = (const float*)d_in[1];
  const float* V = (const float*)d_in[2];
  float* out = (float*)d_out;
  float* ws  = (float*)d_ws;
  const bool useKB = ws_size >= WS_KB_END;

  k0_xn<<<512, 256, 0, stream>>>(x, ws);
  if (useKB) k0c_kn<true ><<<1563, 256, 0, stream>>>(K, ws);
  else       k0c_kn<false><<<1563, 256, 0, stream>>>(K, ws);
  k0b_tr<<<MP/64, 256, 0, stream>>>(V, ws);
  if (useKB) {                               // Path A
    k1b_sum<<<1024, 512, 0, stream>>>(ws, out);
    k2_final<256><<<512, 256, 0, stream>>>(out, ws);
    k3a_main<<<448, 512, 0, stream>>>(ws, out);
    k4_red<true><<<512, 256, 0, stream>>>(ws, out);
  } else {                                   // Path B
    k3b_main<<<224, 512, 0, stream>>>(x, K, ws, out);
    k2_final<112><<<512, 256, 0, stream>>>(out, ws);
    k5_scale<<<dim3((MCOLS/4 + 255)/256, 512), 256, 0, stream>>>(ws, out);
    k4_red<false><<<512, 256, 0, stream>>>(ws, out);
  }
}

// Round 11
// 244.488 us; speedup vs baseline: 1.4490x; 1.1560x over previous
//
#include <hip/hip_runtime.h>
#include <hip/hip_bf16.h>

// GroupNLMSMemory: B=512, D=256, M=100000
// out = [retrieved 512x256 | attn 512x100000] (f32)
// r11: k3a reverted to r8-exact (r10's counted-vmcnt bundle regressed: +25%
//      bank conflicts, 3 bar/tile, sched_barrier pinning). k1b rebuilt with
//      halved LDS redundancy: 128-row blocks, xf[2][8], each B-frag feeds 2
//      MFMAs; grid 512 = 2 blk/CU exact.
// Path A (ws >= 135.4MB): k0,k0c<KB>,k0b -> k1b -> k2<256> -> k3a -> k4<true>
// Path B fallback: k0,k0c<false>,k0b -> k3b -> k2<112> -> k5,k4<false>

#define MCOLS 100000
#define MP    100032
#define DDIM  256
#define CHUNK 1792                 // k3: 28 tiles of 64
#define NTFULL 28
#define NCHUNK 56
#define NSLOT 56
#define CHUNK1 832                 // k1b: 26 tiles of 32
#define NT1   26
#define ATTN_OFF 131072
#define WS_RXN  0
#define WS_RKN  512
#define WS_RCPL 100512
#define WS_XB_BYTE   409600ull
#define WS_VT_BYTE   1048576ull
#define WS_PART_BYTE 52264960ull
#define WS_KB_BYTE   84246528ull
#define WS_KB_END    (WS_KB_BYTE + 2ull*(size_t)MCOLS*DDIM) // 135,446,528

#define GLL(g, l) __builtin_amdgcn_global_load_lds( \
    (const __attribute__((address_space(1))) void*)(g), \
    (__attribute__((address_space(3))) void*)(l), 16, 0, 0)

typedef short short8 __attribute__((ext_vector_type(8)));
typedef float f32x4  __attribute__((ext_vector_type(4)));

static __device__ __forceinline__ unsigned short f2bfu(float f) {
  union { __hip_bfloat16 h; unsigned short u; } cv;
  cv.h = __float2bfloat16(f);
  return cv.u;
}
static __device__ __forceinline__ unsigned int pk2(float a, float b) {
  return (unsigned int)f2bfu(a) | ((unsigned int)f2bfu(b) << 16);
}
static __device__ __forceinline__ short8 pack8(float4 a, float4 b) {
  short8 r;
  r[0] = (short)f2bfu(a.x); r[1] = (short)f2bfu(a.y);
  r[2] = (short)f2bfu(a.z); r[3] = (short)f2bfu(a.w);
  r[4] = (short)f2bfu(b.x); r[5] = (short)f2bfu(b.y);
  r[6] = (short)f2bfu(b.z); r[7] = (short)f2bfu(b.w);
  return r;
}

// ---------------- k0: x norms -> rxn + xb = bf16(10*x/|x|) ----------------
__global__ void k0_xn(const float* __restrict__ x, float* __restrict__ ws) {
  const int b = blockIdx.x, t = threadIdx.x;
  const float v = x[b*DDIM + t];
  float s = v*v;
  #pragma unroll
  for (int mk = 1; mk <= 32; mk <<= 1) s += __shfl_xor(s, mk);
  __shared__ float ps[4];
  if ((t & 63) == 0) ps[t >> 6] = s;
  __syncthreads();
  const float tot = ps[0] + ps[1] + ps[2] + ps[3];
  const float r10 = 10.0f / fmaxf(sqrtf(tot), 1e-12f);
  if (t == 0) ws[WS_RXN + b] = r10;
  unsigned short* xbp = (unsigned short*)((char*)ws + WS_XB_BYTE);
  xbp[b*DDIM + t] = f2bfu(v * r10);
}

// ---------------- k0c: K norms (+ normalized swizzled Kbf16) ----------------
template<bool WRITEKB>
__global__ __launch_bounds__(256) void k0c_kn(const float* __restrict__ K,
                                              float* __restrict__ ws) {
  const int t = threadIdx.x;
  const int mg = blockIdx.x*64 + (t >> 2);
  const int qq = t & 3;
  if (mg >= MCOLS) return;
  const float* kp = K + (size_t)mg*DDIM + 64*qq;
  float4 buf[16];
  float ss = 0.f;
  #pragma unroll
  for (int j = 0; j < 16; ++j) {
    buf[j] = *(const float4*)(kp + 4*j);
    ss += buf[j].x*buf[j].x + buf[j].y*buf[j].y + buf[j].z*buf[j].z + buf[j].w*buf[j].w;
  }
  ss += __shfl_xor(ss, 1); ss += __shfl_xor(ss, 2);
  const float rk = 1.0f / fmaxf(sqrtf(ss), 1e-12f);
  if (qq == 0) ws[WS_RKN + mg] = rk;
  if (WRITEKB) {
    unsigned int* kb = (unsigned int*)((char*)ws + WS_KB_BYTE);
    #pragma unroll
    for (int j = 0; j < 8; ++j) {
      const float4 a = buf[2*j], b2 = buf[2*j+1];
      uint4 u;
      u.x = pk2(a.x*rk, a.y*rk);  u.y = pk2(a.z*rk, a.w*rk);
      u.z = pk2(b2.x*rk, b2.y*rk); u.w = pk2(b2.z*rk, b2.w*rk);
      const int slot = (8*qq + j) ^ (mg & 7);   // 16B-slot XOR swizzle
      *(uint4*)(kb + (size_t)mg*128 + slot*4) = u;
    }
  }
}

// ---------------- k0b: V -> VT bf16 [256][MP], slot^(d&7) swizzled ----------------
__global__ __launch_bounds__(256) void k0b_tr(const float* __restrict__ V,
                                              float* __restrict__ ws) {
  const int t = threadIdx.x;
  const int m0 = blockIdx.x * 64;
  __shared__ float vt_f[64][261];
  #pragma unroll
  for (int i = 0; i < 4; ++i) {
    const int ml = (t >> 4) + 16*i;
    const int mg = m0 + ml;
    #pragma unroll
    for (int j = 0; j < 4; ++j) {
      const int d = 4*(t & 15) + 64*j;
      float4 v = make_float4(0.f, 0.f, 0.f, 0.f);
      if (mg < MCOLS) v = *(const float4*)(V + (size_t)mg*DDIM + d);
      vt_f[ml][d] = v.x; vt_f[ml][d+1] = v.y; vt_f[ml][d+2] = v.z; vt_f[ml][d+3] = v.w;
    }
  }
  __syncthreads();
  unsigned short* vt = (unsigned short*)((char*)ws + WS_VT_BYTE);
  const int tl = t & 15;
  const int s = tl >> 1, hf = tl & 1;
  const int mq = 8*s + 4*hf;
  #pragma unroll
  for (int it = 0; it < 16; ++it) {
    const int d = (t >> 4) + 16*it;
    uint2 u;
    u.x = pk2(vt_f[mq+0][d], vt_f[mq+1][d]);
    u.y = pk2(vt_f[mq+2][d], vt_f[mq+3][d]);
    const int sp = s ^ (d & 7);
    *(uint2*)(vt + (size_t)d*MP + m0 + sp*8 + 4*hf) = u;
  }
}

// ---------------- staging helpers (GLL, linear dst) ----------------
static __device__ __forceinline__ void stage_k(const char* __restrict__ kb,
                                               int m0, int w, int l,
                                               unsigned short (*klds)[256]) {
  #pragma unroll
  for (int i = 0; i < 4; ++i) {
    int r = m0 + w*8 + i*2 + (l >> 5);
    r = min(r, MCOLS - 1);
    const char* g = kb + (size_t)r*512 + (l & 31)*16;
    char* dst = (char*)&klds[w*8 + i*2][0];
    GLL(g, dst);
  }
}
static __device__ __forceinline__ void stage_k32(const char* __restrict__ kb,
                                                 int m0, int w, int l,
                                                 unsigned short (*klds)[256]) {
  #pragma unroll
  for (int i = 0; i < 2; ++i) {
    int r = m0 + w*4 + i*2 + (l >> 5);
    r = min(r, MCOLS - 1);
    const char* g = kb + (size_t)r*512 + (l & 31)*16;
    char* dst = (char*)&klds[w*4 + i*2][0];
    GLL(g, dst);
  }
}
static __device__ __forceinline__ void stage_vt(const char* __restrict__ vtb,
                                                int m1, int w, int l,
                                                unsigned short (*vtl)[64]) {
  #pragma unroll
  for (int i = 0; i < 4; ++i) {
    const int d = w*32 + i*8 + (l >> 3);
    const int ms = min(m1 + (l & 7)*8, MP - 8);
    const char* g = vtb + ((size_t)d*MP + ms)*2;
    char* dst = (char*)&vtl[w*32 + i*8][0];
    GLL(g, dst);
  }
}

// ---------------- k1b: sum-of-exp, 128-row blocks, B-frag reuse x2 ----------------
__global__ __launch_bounds__(512, 4) void k1b_sum(const float* __restrict__ ws,
                                                  float* __restrict__ out) {
  const int bid = blockIdx.x;                 // 512 = 8 xg * 16 cg * 4 rb
  const int xg = bid & 7, i = bid >> 3;
  const int c = xg + 8*(i & 15), rb = i >> 4; // co-XCD chunks, c in 0..127
  const int t = threadIdx.x, w = t >> 6, l = t & 63, q = l >> 4, ln = l & 15;
  const int ar = w & 3, h = w >> 2, l7 = ln & 7;
  __shared__ __align__(16) unsigned short klds2[2][32][256];  // 32KB dbuf
  const char* kb = (const char*)ws + WS_KB_BYTE;
  const unsigned short* xb = (const unsigned short*)((const char*)ws + WS_XB_BYTE);
  const int R0 = rb*128;

  short8 xf[2][8];                            // 2 row-strips per wave
  #pragma unroll
  for (int as = 0; as < 2; ++as) {
    const int row = R0 + 32*ar + 16*as + ln;
    #pragma unroll
    for (int kk = 0; kk < 8; ++kk)
      xf[as][kk] = *(const short8*)(xb + row*DDIM + 32*kk + 8*q);
  }
  float lpr[2][4] = {{0.f,0.f,0.f,0.f},{0.f,0.f,0.f,0.f}};
  const int mbase = c*CHUNK1;
  const int rem = MCOLS - mbase;
  const int nt = rem <= 0 ? 0 : min(NT1, (rem + 31) >> 5);

  if (nt > 0) {
    stage_k32(kb, mbase, w, l, klds2[0]);
    __syncthreads();
    for (int mt = 0; mt < nt; ++mt) {
      const int cur = mt & 1;
      const int m0 = mbase + mt*32;
      if (mt + 1 < nt) stage_k32(kb, m0 + 32, w, l, klds2[cur ^ 1]);
      const char* kbase = (const char*)&klds2[cur][0][0];
      const int row0 = 16*h + ln;             // wave's m-col within tile
      f32x4 acc[2];
      { f32x4 z = {0.f,0.f,0.f,0.f}; acc[0] = z; acc[1] = z; }
      #pragma unroll
      for (int kk = 0; kk < 8; ++kk) {
        const int sl = ((q + 4*kk) ^ l7) << 4;
        const short8 b0 = *(const short8*)(kbase + row0*512 + sl);
        acc[0] = __builtin_amdgcn_mfma_f32_16x16x32_bf16(xf[0][kk], b0, acc[0], 0,0,0);
        acc[1] = __builtin_amdgcn_mfma_f32_16x16x32_bf16(xf[1][kk], b0, acc[1], 0,0,0);
      }
      const int mr = m0 + row0;
      const bool ok = mr < MCOLS;
      #pragma unroll
      for (int as = 0; as < 2; ++as)
        #pragma unroll
        for (int r = 0; r < 4; ++r)
          lpr[as][r] += ok ? __expf(acc[as][r]) : 0.f;
      __syncthreads();
    }
  }
  #pragma unroll
  for (int as = 0; as < 2; ++as)
    #pragma unroll
    for (int r = 0; r < 4; ++r) {
      float s = lpr[as][r];
      s += __shfl_xor(s, 1); s += __shfl_xor(s, 2);
      s += __shfl_xor(s, 4); s += __shfl_xor(s, 8);
      if (ln == 0)
        out[(size_t)(c*2 + h)*512 + R0 + 32*ar + 16*as + 4*q + r] = s;
    }
}

// ---------------- k2: merge chunk sums -> 1/l ----------------
template<int NSUM>
__global__ void k2_final(const float* __restrict__ out, float* __restrict__ ws) {
  const int b = blockIdx.x, t = threadIdx.x;   // 512 x 256
  float v = (t < NSUM) ? out[(size_t)t*512 + b] : 0.f;
  #pragma unroll
  for (int mk = 1; mk <= 32; mk <<= 1) v += __shfl_xor(v, mk);
  __shared__ float s2[4];
  if ((t & 63) == 0) s2[t >> 6] = v;
  __syncthreads();
  if (t == 0) ws[WS_RCPL + b] = 1.0f / (s2[0] + s2[1] + s2[2] + s2[3]);
}

// ---------------- k3a (path A): r8-exact fused attn-write + PV ----------------
__global__ __launch_bounds__(512, 4) void k3a_main(float* __restrict__ ws,
                                                   float* __restrict__ out) {
  const int bid = blockIdx.x;                 // 448: co-XCD map
  const int xg = bid & 7, i = bid >> 3;
  const int c = xg + 8*(i % 7), rb = i / 7;
  const int t = threadIdx.x, w = t >> 6, l = t & 63, q = l >> 4, ln = l & 15;
  const int ar = w & 3, h = w >> 2, l7 = ln & 7;
  __shared__ __align__(16) unsigned short klds[64][256];   // 32KB single
  __shared__ __align__(16) unsigned short vtl[256][64];    // 32KB single
  __shared__ __align__(16) unsigned short plds[64][64];    // 8KB XOR-swizzled
  const char* kb  = (const char*)ws + WS_KB_BYTE;
  const char* vtb = (const char*)ws + WS_VT_BYTE;
  const unsigned short* xb = (const unsigned short*)((const char*)ws + WS_XB_BYTE);
  const int R0 = rb*64;

  short8 xf[8];
  {
    const int row = R0 + 16*ar + ln;
    #pragma unroll
    for (int kk = 0; kk < 8; ++kk)
      xf[kk] = *(const short8*)(xb + row*DDIM + 32*kk + 8*q);
  }
  float rlq[4];
  #pragma unroll
  for (int r = 0; r < 4; ++r)
    rlq[r] = ws[WS_RCPL + R0 + 16*ar + 4*q + r];
  f32x4 apv[8];
  #pragma unroll
  for (int dx = 0; dx < 8; ++dx) { f32x4 z = {0.f,0.f,0.f,0.f}; apv[dx] = z; }
  const int d2 = 128*h;
  float* attn = out + ATTN_OFF;
  const int mbase = c*CHUNK;
  const int nt = min(NTFULL, (MCOLS - mbase + 63) >> 6);
  unsigned short* pf = &plds[0][0];

  stage_k(kb, mbase, w, l, klds);
  __syncthreads();

  for (int mt = 0; mt < nt; ++mt) {
    const int m0 = mbase + mt*64;
    stage_vt(vtb, m0, w, l, vtl);            // VT(t), overlaps QK; drains at bar1
    // ---- QK ----
    const int row0 = 32*h + ln;
    f32x4 acc[2];
    { f32x4 z = {0.f,0.f,0.f,0.f}; acc[0] = z; acc[1] = z; }
    #pragma unroll
    for (int kk = 0; kk < 8; ++kk) {
      const int sl = ((q + 4*kk) ^ l7) << 4;
      const short8 b0 = *(const short8*)((const char*)&klds[0][0] + row0*512 + sl);
      const short8 b1 = *(const short8*)((const char*)&klds[0][0] + (row0 + 16)*512 + sl);
      acc[0] = __builtin_amdgcn_mfma_f32_16x16x32_bf16(xf[kk], b0, acc[0], 0,0,0);
      acc[1] = __builtin_amdgcn_mfma_f32_16x16x32_bf16(xf[kk], b1, acc[1], 0,0,0);
    }
    const int mr0 = m0 + row0, mr1 = mr0 + 16;
    const bool ok0 = mr0 < MCOLS, ok1 = mr1 < MCOLS;
    #pragma unroll
    for (int r = 0; r < 4; ++r) {
      const int rowl = 16*ar + 4*q + r;
      const float p0v = ok0 ? __expf(acc[0][r]) : 0.f;
      const float p1v = ok1 ? __expf(acc[1][r]) : 0.f;
      float* arow = attn + (size_t)(R0 + rowl)*MCOLS;
      if (ok0) arow[mr0] = p0v*rlq[r];
      if (ok1) arow[mr1] = p1v*rlq[r];
      const int r7 = rowl & 7;
      pf[rowl*64 + ((((ln>>3) + 4*h    ) ^ r7) << 3) + (ln & 7)] = f2bfu(p0v);
      pf[rowl*64 + ((((ln>>3) + 4*h + 2) ^ r7) << 3) + (ln & 7)] = f2bfu(p1v);
    }
    __syncthreads();                         // bar1: VT staged, plds ready, klds free
    if (mt + 1 < nt) stage_k(kb, m0 + 64, w, l, klds);  // K(t+1), overlaps PV
    // ---- PV ----
    const int prow = 16*ar + ln;
    const short8 af0 = *(const short8*)(pf + prow*64 + ((q       ^ l7) << 3));
    const short8 af1 = *(const short8*)(pf + prow*64 + (((4 + q) ^ l7) << 3));
    #pragma unroll
    for (int dx = 0; dx < 8; ++dx) {
      const int R = d2 + 16*dx + ln;
      const char* vr = (const char*)&vtl[0][0] + R*128;
      const short8 bv0 = *(const short8*)(vr + ((q       ^ l7) << 4));
      const short8 bv1 = *(const short8*)(vr + (((4 + q) ^ l7) << 4));
      apv[dx] = __builtin_amdgcn_mfma_f32_16x16x32_bf16(af0, bv0, apv[dx], 0,0,0);
      apv[dx] = __builtin_amdgcn_mfma_f32_16x16x32_bf16(af1, bv1, apv[dx], 0,0,0);
    }
    __syncthreads();                         // bar2: vtl reads done, K(t+1) staged
  }

  float* part = (float*)((char*)ws + WS_PART_BYTE);
  #pragma unroll
  for (int dx = 0; dx < 8; ++dx)
    #pragma unroll
    for (int r = 0; r < 4; ++r)
      part[((size_t)c*512 + R0 + 16*ar + 4*q + r)*256 + d2 + 16*dx + ln]
        = apv[dx][r]*rlq[r];
}

// ---------------- k3b (path B fallback): direct-load, unnorm + sums ----------------
static __device__ __forceinline__ void load_xf(const float* __restrict__ x,
                                               int brow0, int q, int ln,
                                               short8 xf[2][8]) {
  #pragma unroll
  for (int as = 0; as < 2; ++as) {
    const int row = brow0 + 16*as + ln;
    #pragma unroll
    for (int kk = 0; kk < 8; ++kk) {
      const float* p = x + row*DDIM + 32*kk + 8*q;
      xf[as][kk] = pack8(*(const float4*)p, *(const float4*)(p + 4));
    }
  }
}

__global__ __launch_bounds__(512, 2) void k3b_main(const float* __restrict__ x,
                                                   const float* __restrict__ K,
                                                   float* __restrict__ ws,
                                                   float* __restrict__ out) {
  const int bid = blockIdx.x;                 // 224 = 56 chunks * 4 rb
  const int c = bid >> 2, rb = bid & 3;
  const int t = threadIdx.x, w = t >> 6, l = t & 63, q = l >> 4, ln = l & 15;
  const int h = w & 1, rg = w >> 1;
  __shared__ __align__(16) unsigned short plds[2][128][72];
  const int R0 = rb*128;
  short8 xf[2][8];
  const int brow0 = R0 + 32*rg;
  load_xf(x, brow0, q, ln, xf);
  float rxn[2][4];
  #pragma unroll
  for (int as = 0; as < 2; ++as)
    #pragma unroll
    for (int r = 0; r < 4; ++r)
      rxn[as][r] = ws[WS_RXN + brow0 + 16*as + 4*q + r];
  float lpr[2][4] = {{0.f,0.f,0.f,0.f},{0.f,0.f,0.f,0.f}};
  f32x4 apv[2][8];
  #pragma unroll
  for (int bs = 0; bs < 2; ++bs)
    #pragma unroll
    for (int dx = 0; dx < 8; ++dx) { f32x4 z = {0.f,0.f,0.f,0.f}; apv[bs][dx] = z; }
  const int b2 = 32*(w & 3), d2 = 128*(w >> 2);
  const unsigned short* vt = (const unsigned short*)((const char*)ws + WS_VT_BYTE);
  const float* rknw = ws + WS_RKN;
  float* attn = out + ATTN_OFF;
  const int mbase = c*CHUNK;
  const int nt = min(NTFULL, (MCOLS - mbase + 63) >> 6);
  const int l7 = ln & 7;

  for (int mt = 0; mt < nt; ++mt) {
    const int m0 = mbase + mt*64;
    const int mr0 = m0 + 32*h + ln, mr1 = mr0 + 16;
    const int kr0 = min(mr0, MCOLS-1), kr1 = min(mr1, MCOLS-1);
    f32x4 acc[2][2];
    #pragma unroll
    for (int as = 0; as < 2; ++as)
      #pragma unroll
      for (int mm = 0; mm < 2; ++mm) { f32x4 z = {0.f,0.f,0.f,0.f}; acc[as][mm] = z; }
    const float* p0 = K + (size_t)kr0*DDIM + 8*q;
    const float* p1 = K + (size_t)kr1*DDIM + 8*q;
    #pragma unroll
    for (int kk = 0; kk < 8; ++kk) {
      const short8 b0 = pack8(*(const float4*)(p0 + 32*kk), *(const float4*)(p0 + 32*kk + 4));
      const short8 b1 = pack8(*(const float4*)(p1 + 32*kk), *(const float4*)(p1 + 32*kk + 4));
      acc[0][0] = __builtin_amdgcn_mfma_f32_16x16x32_bf16(xf[0][kk], b0, acc[0][0], 0,0,0);
      acc[0][1] = __builtin_amdgcn_mfma_f32_16x16x32_bf16(xf[0][kk], b1, acc[0][1], 0,0,0);
      acc[1][0] = __builtin_amdgcn_mfma_f32_16x16x32_bf16(xf[1][kk], b0, acc[1][0], 0,0,0);
      acc[1][1] = __builtin_amdgcn_mfma_f32_16x16x32_bf16(xf[1][kk], b1, acc[1][1], 0,0,0);
    }
    const float rk0 = rknw[kr0], rk1 = rknw[kr1];
    const bool ok0 = mr0 < MCOLS, ok1 = mr1 < MCOLS;
    #pragma unroll
    for (int as = 0; as < 2; ++as)
      #pragma unroll
      for (int r = 0; r < 4; ++r) {
        const int rowl = 32*rg + 16*as + 4*q + r;
        const float p0v = ok0 ? __expf(acc[as][0][r]*rxn[as][r]*rk0) : 0.f;
        const float p1v = ok1 ? __expf(acc[as][1][r]*rxn[as][r]*rk1) : 0.f;
        float* arow = attn + (size_t)(R0 + rowl)*MCOLS;
        if (ok0) arow[mr0] = p0v;
        if (ok1) arow[mr1] = p1v;
        lpr[as][r] += p0v + p1v;
        plds[mt & 1][rowl][32*h + ln]      = f2bfu(p0v);
        plds[mt & 1][rowl][32*h + 16 + ln] = f2bfu(p1v);
      }
    __syncthreads();
    const unsigned short (*pb)[72] = plds[mt & 1];
    const short8 af00 = *(const short8*)&pb[b2 + ln][8*q];
    const short8 af01 = *(const short8*)&pb[b2 + ln][32 + 8*q];
    const short8 af10 = *(const short8*)&pb[b2 + 16 + ln][8*q];
    const short8 af11 = *(const short8*)&pb[b2 + 16 + ln][32 + 8*q];
    #pragma unroll
    for (int dx = 0; dx < 8; ++dx) {
      const int R = d2 + 16*dx + ln;
      const size_t rbase = (size_t)R*MP + m0;
      const short8 bv0 = *(const short8*)(vt + rbase + ((q     ^ (R & 7)) << 3));
      const short8 bv1 = *(const short8*)(vt + rbase + (((4+q) ^ (R & 7)) << 3));
      apv[0][dx] = __builtin_amdgcn_mfma_f32_16x16x32_bf16(af00, bv0, apv[0][dx], 0,0,0);
      apv[0][dx] = __builtin_amdgcn_mfma_f32_16x16x32_bf16(af01, bv1, apv[0][dx], 0,0,0);
      apv[1][dx] = __builtin_amdgcn_mfma_f32_16x16x32_bf16(af10, bv0, apv[1][dx], 0,0,0);
      apv[1][dx] = __builtin_amdgcn_mfma_f32_16x16x32_bf16(af11, bv1, apv[1][dx], 0,0,0);
    }
  }

  #pragma unroll
  for (int as = 0; as < 2; ++as)
    #pragma unroll
    for (int r = 0; r < 4; ++r) {
      float s = lpr[as][r];
      s += __shfl_xor(s, 1); s += __shfl_xor(s, 2);
      s += __shfl_xor(s, 4); s += __shfl_xor(s, 8);
      if (ln == 0)
        out[(size_t)(c*2 + h)*512 + brow0 + 16*as + 4*q + r] = s;
    }
  float* part = (float*)((char*)ws + WS_PART_BYTE);
  #pragma unroll
  for (int bs = 0; bs < 2; ++bs)
    #pragma unroll
    for (int dx = 0; dx < 8; ++dx)
      #pragma unroll
      for (int r = 0; r < 4; ++r)
        part[((size_t)c*512 + R0 + b2 + 16*bs + 4*q + r)*256 + d2 + 16*dx + ln]
          = apv[bs][dx][r];
}

// ---------------- k4: reduce retrieved partials ----------------
template<bool NORM>
__global__ void k4_red(const float* __restrict__ ws, float* __restrict__ out) {
  const int b = blockIdx.x, t = threadIdx.x;
  const float* part = (const float*)((const char*)ws + WS_PART_BYTE);
  float acc = 0.f;
  for (int cc = 0; cc < NSLOT; ++cc)
    acc += part[((size_t)cc*512 + b)*256 + t];
  if (!NORM) acc *= ws[WS_RCPL + b];
  out[b*DDIM + t] = acc;
}

// ---------------- k5 (path B): rescale attn by 1/l (f32x4) ----------------
__global__ void k5_scale(const float* __restrict__ ws, float* __restrict__ out) {
  const int row = blockIdx.y;
  const int i4 = blockIdx.x*256 + threadIdx.x;
  if (i4 >= MCOLS/4) return;
  const float s = ws[WS_RCPL + row];
  float4* p = (float4*)(out + ATTN_OFF + (size_t)row*MCOLS) + i4;
  float4 v = *p;
  v.x *= s; v.y *= s; v.z *= s; v.w *= s;
  *p = v;
}

extern "C" void kernel_launch(void* const* d_in, const int* in_sizes, int n_in,
                              void* d_out, int out_size, void* d_ws, size_t ws_size,
                              hipStream_t stream) {
  const float* x = (const float*)d_in[0];
  const float* K = (const float*)d_in[1];
  const float* V = (const float*)d_in[2];
  float* out = (float*)d_out;
  float* ws  = (float*)d_ws;
  const bool useKB = ws_size >= WS_KB_END;

  k0_xn<<<512, 256, 0, stream>>>(x, ws);
  if (useKB) k0c_kn<true ><<<1563, 256, 0, stream>>>(K, ws);
  else       k0c_kn<false><<<1563, 256, 0, stream>>>(K, ws);
  k0b_tr<<<MP/64, 256, 0, stream>>>(V, ws);
  if (useKB) {                               // Path A
    k1b_sum<<<512, 512, 0, stream>>>(ws, out);
    k2_final<256><<<512, 256, 0, stream>>>(out, ws);
    k3a_main<<<448, 512, 0, stream>>>(ws, out);
    k4_red<true><<<512, 256, 0, stream>>>(ws, out);
  } else {                                   // Path B
    k3b_main<<<224, 512, 0, stream>>>(x, K, ws, out);
    k2_final<112><<<512, 256, 0, stream>>>(out, ws);
    k5_scale<<<dim3((MCOLS/4 + 255)/256, 512), 256, 0, stream>>>(ws, out);
    k4_red<false><<<512, 256, 0, stream>>>(ws, out);
  }
}